// Round 15
// baseline (47132.233 us; speedup 1.0000x reference)
//
#include <hip/hip_runtime.h>
#include <math.h>

// VanillaRNN B=256,T=512,H=1024,O=10 — bit-exact replication of reference CPU
// fp32 trajectory. Decoded arithmetic (R5-R7 oracle): kc=512 panels, no-FMA
// chains (__fmul_rn/__fadd_rn, k ascending, panels joined in order), tanh =
// clamp ±7.99881172180175781 + fmaf Horner + IEEE div, no-FMA xp.
//
// R15 = R14 (PASSING, 34.8 ms) + TLP + explicit prefetch:
//  - 512 threads (8 waves, 2/SIMD — was 1/SIMD); thread = 2 rows x 1 col.
//  - depth-2 software pipeline on global loads (h float4, panel1 W scalars),
//    hand-unrolled x2 with named even/odd buffers (static indices).
//  - W panel0 in LDS [k][lane] (R14-proven, 0 conflicts); panel1 W global.
//  - sync / XCD-local mapping / chain order / epilogue: R14 verbatim.

#define HH 1024
#define TT 512
#define BB 256
#define OO 10
#define NG 16      // row groups (16 rows)
#define NCT 16     // col tiles (64 cols)
#define NTH 512
#define KH 512     // panel size

__device__ __forceinline__ float tanh_ref(float x) {
    const float kClamp = 7.99881172180175781f;
    float xc = fminf(fmaxf(x, -kClamp), kClamp);
    float x2 = __fmul_rn(xc, xc);
    float p = -2.76076847742355e-16f;
    p = fmaf(x2, p,  2.00018790482477e-13f);
    p = fmaf(x2, p, -8.60467152213735e-11f);
    p = fmaf(x2, p,  5.12229709037114e-08f);
    p = fmaf(x2, p,  1.48572235717979e-05f);
    p = fmaf(x2, p,  6.37261928875436e-04f);
    p = fmaf(x2, p,  4.89352455891786e-03f);
    p = __fmul_rn(xc, p);
    float q = 1.19825839466702e-06f;
    q = fmaf(x2, q, 1.18534705686654e-04f);
    q = fmaf(x2, q, 2.26843463243900e-03f);
    q = fmaf(x2, q, 4.89352518554385e-03f);
    float r = __fdiv_rn(p, q);
    return (fabsf(x) < 0.0004f) ? x : r;
}

#define MACC(acc, hv, wv) acc = __fadd_rn(acc, __fmul_rn(hv, wv))

__global__ void __launch_bounds__(NTH, 2) rnn_persist(
    const float* __restrict__ x, const float* __restrict__ Whx,
    const float* __restrict__ Whh, const float* __restrict__ Wph,
    const float* __restrict__ bh, const float* __restrict__ bo,
    float* __restrict__ out, float* __restrict__ ws)
{
    __shared__ float wlds[KH][64];      // 128 KB: W[k<512][j0..j0+64)

    const int bid  = blockIdx.x;        // 0..255
    const int ct   = (bid >> 3) & 15;                 // col tile
    const int g    = ((bid & 7) << 1) | (bid >> 7);   // row group; bid%8 == g>>1
    const int tid  = threadIdx.x;
    const int w    = tid >> 6;          // wave 0..7
    const int lane = tid & 63;
    const int j0   = ct * 64;
    const int j    = j0 + lane;         // this thread's column
    const int r0w  = g * 16 + w * 2;    // this thread's first row (2 rows)

    float* hAbuf = ws;                  // [256][1024]
    float* hBbuf = ws + (BB * HH);
    int*   ctr   = (int*)(ws + 2 * BB * HH);  // [16], memset 0 pre-launch

    const float whx_j = Whx[j];
    const float bh_j  = bh[j];

    // ---- one-time W panel0 preload: 8192 float4 slots, coalesced ----
    #pragma unroll
    for (int i = 0; i < 16; ++i) {
        const int s = tid + i * NTH;     // 0..8191
        const int k = s >> 4;            // 0..511
        const int c = s & 15;            // float4 within 64-col row
        ((float4*)wlds)[s] = ((const float4*)(Whh + (size_t)k * HH + j0))[c];
    }

    // ---- zero-init hA rows, then group sync (R14 verbatim; fences wlds too) ----
    hAbuf[(size_t)(r0w + 0) * HH + j] = 0.0f;
    hAbuf[(size_t)(r0w + 1) * HH + j] = 0.0f;
    __threadfence();
    __syncthreads();
    if (tid == 0) {
        __hip_atomic_fetch_add(&ctr[g], 1, __ATOMIC_RELEASE, __HIP_MEMORY_SCOPE_AGENT);
        while (__hip_atomic_load(&ctr[g], __ATOMIC_ACQUIRE, __HIP_MEMORY_SCOPE_AGENT) < NCT)
            __builtin_amdgcn_s_sleep(2);
    }
    __syncthreads();
    __threadfence();

    for (int t = 0; t < TT; ++t) {
        const float* hsrc = (t & 1) ? hBbuf : hAbuf;
        float*       hdst = (t & 1) ? hAbuf : hBbuf;

        const float* h0p = hsrc + (size_t)(r0w + 0) * HH;
        const float* h1p = hsrc + (size_t)(r0w + 1) * HH;
        const float* wg  = Whh + (size_t)KH * HH + j;   // panel1 W[512+k][j]

        float a0 = 0.f, a1 = 0.f;   // panel0 chains (2 rows)
        float b0 = 0.f, b1 = 0.f;   // panel1 chains

        // ---- depth-2 pipeline: preload sub-iters 0 (k4=0) and 1 (k4=4) ----
        float4 ha0_0 = *(const float4*)(h0p + 0);
        float4 ha1_0 = *(const float4*)(h1p + 0);
        float4 hb0_0 = *(const float4*)(h0p + KH + 0);
        float4 hb1_0 = *(const float4*)(h1p + KH + 0);
        float  v0_0 = wg[0 * HH], v1_0 = wg[1 * HH], v2_0 = wg[2 * HH], v3_0 = wg[3 * HH];
        float4 ha0_1 = *(const float4*)(h0p + 4);
        float4 ha1_1 = *(const float4*)(h1p + 4);
        float4 hb0_1 = *(const float4*)(h0p + KH + 4);
        float4 hb1_1 = *(const float4*)(h1p + KH + 4);
        float  v0_1 = wg[4 * HH], v1_1 = wg[5 * HH], v2_1 = wg[6 * HH], v3_1 = wg[7 * HH];

        #pragma unroll 1
        for (int k4 = 0; k4 < KH; k4 += 8) {
            // ===== even sub-iter (k = k4..k4+3): consume *_0, prefetch k4+8 =====
            {
                const float4 ha0 = ha0_0, ha1 = ha1_0, hb0 = hb0_0, hb1 = hb1_0;
                const float v0 = v0_0, v1 = v1_0, v2 = v2_0, v3 = v3_0;
                const int kn = (k4 + 8) & (KH - 1);     // wrap; tail prefetch unused
                ha0_0 = *(const float4*)(h0p + kn);
                ha1_0 = *(const float4*)(h1p + kn);
                hb0_0 = *(const float4*)(h0p + KH + kn);
                hb1_0 = *(const float4*)(h1p + KH + kn);
                v0_0 = wg[(size_t)(kn + 0) * HH];
                v1_0 = wg[(size_t)(kn + 1) * HH];
                v2_0 = wg[(size_t)(kn + 2) * HH];
                v3_0 = wg[(size_t)(kn + 3) * HH];
                const float w0 = wlds[k4 + 0][lane];
                const float w1 = wlds[k4 + 1][lane];
                const float w2 = wlds[k4 + 2][lane];
                const float w3 = wlds[k4 + 3][lane];
                // k ascending per panel — chain order is the correctness contract
                MACC(a0, ha0.x, w0); MACC(a1, ha1.x, w0);
                MACC(b0, hb0.x, v0); MACC(b1, hb1.x, v0);
                MACC(a0, ha0.y, w1); MACC(a1, ha1.y, w1);
                MACC(b0, hb0.y, v1); MACC(b1, hb1.y, v1);
                MACC(a0, ha0.z, w2); MACC(a1, ha1.z, w2);
                MACC(b0, hb0.z, v2); MACC(b1, hb1.z, v2);
                MACC(a0, ha0.w, w3); MACC(a1, ha1.w, w3);
                MACC(b0, hb0.w, v3); MACC(b1, hb1.w, v3);
            }
            // ===== odd sub-iter (k = k4+4..k4+7): consume *_1, prefetch k4+12 =====
            {
                const float4 ha0 = ha0_1, ha1 = ha1_1, hb0 = hb0_1, hb1 = hb1_1;
                const float v0 = v0_1, v1 = v1_1, v2 = v2_1, v3 = v3_1;
                const int kn = (k4 + 12) & (KH - 1);
                ha0_1 = *(const float4*)(h0p + kn);
                ha1_1 = *(const float4*)(h1p + kn);
                hb0_1 = *(const float4*)(h0p + KH + kn);
                hb1_1 = *(const float4*)(h1p + KH + kn);
                v0_1 = wg[(size_t)(kn + 0) * HH];
                v1_1 = wg[(size_t)(kn + 1) * HH];
                v2_1 = wg[(size_t)(kn + 2) * HH];
                v3_1 = wg[(size_t)(kn + 3) * HH];
                const float w0 = wlds[k4 + 4][lane];
                const float w1 = wlds[k4 + 5][lane];
                const float w2 = wlds[k4 + 6][lane];
                const float w3 = wlds[k4 + 7][lane];
                MACC(a0, ha0.x, w0); MACC(a1, ha1.x, w0);
                MACC(b0, hb0.x, v0); MACC(b1, hb1.x, v0);
                MACC(a0, ha0.y, w1); MACC(a1, ha1.y, w1);
                MACC(b0, hb0.y, v1); MACC(b1, hb1.y, v1);
                MACC(a0, ha0.z, w2); MACC(a1, ha1.z, w2);
                MACC(b0, hb0.z, v2); MACC(b1, hb1.z, v2);
                MACC(a0, ha0.w, w3); MACC(a1, ha1.w, w3);
                MACC(b0, hb0.w, v3); MACC(b1, hb1.w, v3);
            }
        }

        // join panels (p0 then p1), xp, z, tanh, store (contract order)
        {
            const float m0 = __fadd_rn(a0, b0);
            const float m1 = __fadd_rn(a1, b1);
            const float xv0 = x[(r0w + 0) * TT + t];
            const float xv1 = x[(r0w + 1) * TT + t];
            hdst[(size_t)(r0w + 0) * HH + j] =
                tanh_ref(__fadd_rn(__fadd_rn(__fmul_rn(xv0, whx_j), bh_j), m0));
            hdst[(size_t)(r0w + 1) * HH + j] =
                tanh_ref(__fadd_rn(__fadd_rn(__fmul_rn(xv1, whx_j), bh_j), m1));
        }

        // row-group sync (monotonic counter, agent scope — R14 verbatim)
        __threadfence();
        __syncthreads();
        if (tid == 0) {
            __hip_atomic_fetch_add(&ctr[g], 1, __ATOMIC_RELEASE, __HIP_MEMORY_SCOPE_AGENT);
            const int target = NCT * (t + 2);
            while (__hip_atomic_load(&ctr[g], __ATOMIC_ACQUIRE, __HIP_MEMORY_SCOPE_AGENT) < target)
                __builtin_amdgcn_s_sleep(2);
        }
        __syncthreads();
        __threadfence();
    }

    // ---- epilogue: out = h_final @ Wph + bo (h_final in hAbuf; TT even) ----
    if (ct == 0) {
        #pragma unroll 1
        for (int p = w; p < 16 * OO; p += 8) {
            const int rr = p / OO, o = p % OO;
            const int row = g * 16 + rr;
            float v = 0.0f;
            #pragma unroll
            for (int m = 0; m < HH / 64; ++m) {
                const int k = lane + (m << 6);
                v = fmaf(hAbuf[(size_t)row * HH + k], Wph[k * OO + o], v);
            }
            #pragma unroll
            for (int s = 32; s > 0; s >>= 1) v += __shfl_down(v, s, 64);
            if (lane == 0) out[row * OO + o] = v + bo[o];
        }
    }
}

extern "C" void kernel_launch(void* const* d_in, const int* in_sizes, int n_in,
                              void* d_out, int out_size, void* d_ws, size_t ws_size,
                              hipStream_t stream) {
    const float* x   = (const float*)d_in[0];
    const float* Whx = (const float*)d_in[1];
    const float* Whh = (const float*)d_in[2];
    const float* Wph = (const float*)d_in[3];
    const float* bh  = (const float*)d_in[4];
    const float* bo  = (const float*)d_in[5];
    float* out = (float*)d_out;
    float* ws  = (float*)d_ws;

    // reset row-group counters (R14 verbatim region, 64 B at 2 MB offset)
    hipMemsetAsync((char*)d_ws + (size_t)2 * BB * HH * 4, 0, NG * sizeof(int), stream);

    void* args[] = {(void*)&x, (void*)&Whx, (void*)&Whh, (void*)&Wph,
                    (void*)&bh, (void*)&bo, (void*)&out, (void*)&ws};
    hipLaunchCooperativeKernel((void*)rnn_persist, dim3(NG * NCT), dim3(NTH),
                               args, 0, stream);
}